// Round 1
// baseline (1591.982 us; speedup 1.0000x reference)
//
#include <hip/hip_runtime.h>
#include <hip/hip_bf16.h>
#include <cstddef>

#define NXX 512
#define NUU 128
#define NDD 64
#define BB  256
#define TT  256
#define CL  8
#define NC  32
#define BS  (BB * NXX)     // one slab in elements (256*512)
#define MS  (NXX * NXX)    // one 512x512 matrix in elements
#define LDK 32             // LDS row stride (bf16) for 128x32 staging tiles
#define SR  16             // batch rows per scan block (was 32)

typedef __attribute__((ext_vector_type(8))) short short8;
typedef __attribute__((ext_vector_type(8))) unsigned short ushort8;
typedef __attribute__((ext_vector_type(4))) unsigned short ushort4v;
typedef __attribute__((ext_vector_type(4))) float f32x4;

__device__ __forceinline__ unsigned short f2bf(float f) {
    union { float f; unsigned u; } v; v.f = f;
    unsigned r = v.u + 0x7FFFu + ((v.u >> 16) & 1u);   // RNE
    return (unsigned short)(r >> 16);
}
__device__ __forceinline__ float bf2f(unsigned short h) {
    union { unsigned u; float f; } v; v.u = ((unsigned)h) << 16;
    return v.f;
}

// ---------------------------------------------------------------------------
// 128x128-tile GEMM machinery (used by k_pow / k_hs) — proven in round 2.
// ---------------------------------------------------------------------------
enum StageKind { SK_BF16_NAT, SK_BF16_TRANS };

template<StageKind SK>
__device__ __forceinline__ void stage_tile(const void* src, int ld, int r0, int k0,
                                           unsigned short (*S)[LDK])
{
    const int tid = threadIdx.x;
    if constexpr (SK == SK_BF16_NAT) {
        const unsigned short* s = (const unsigned short*)src;
        const int wave = tid >> 6, lane = tid & 63;
#pragma unroll
        for (int i = 0; i < 2; ++i) {
            int rb = wave * 16 + i * 64;      // wave-uniform row base
            int r  = rb + (lane >> 2);
            int c  = (lane & 3) << 3;
            const unsigned short* g = s + (size_t)(r0 + r) * ld + k0 + c;
            __builtin_amdgcn_global_load_lds(
                (const __attribute__((address_space(1))) void*)g,
                (__attribute__((address_space(3))) void*)&S[rb][0],
                16, 0, 0);
        }
    } else { // SK_BF16_TRANS
        const unsigned short* s = (const unsigned short*)src;
#pragma unroll
        for (int i = 0; i < 2; ++i) {
            int idx = tid + i * 256;
            int m   = idx >> 4;               // 0..31 contraction row
            int c   = (idx & 15) << 3;        // 0..120 output col
            ushort8 v = *(const ushort8*)(s + (size_t)(k0 + m) * ld + r0 + c);
#pragma unroll
            for (int j = 0; j < 8; ++j) S[c + j][m] = v[j];
        }
    }
}

template<StageKind AK, StageKind BK>
__device__ __forceinline__ void gemm_mainloop(
    f32x4 (&acc)[4][4],
    const void* A, int lda, const void* B, int ldb,
    int K, int row0, int n0,
    unsigned short (*As)[LDK], unsigned short (*Bs)[LDK])
{
    const int tid  = threadIdx.x;
    const int lane = tid & 63;
    const int wave = tid >> 6;
    const int wm   = (wave >> 1) * 64;
    const int wn   = (wave & 1) * 64;
    const int l16  = lane & 15;
    const int quad = lane >> 4;

    for (int k0 = 0; k0 < K; k0 += 32) {
        __syncthreads();
        stage_tile<AK>(A, lda, row0, k0, As);
        stage_tile<BK>(B, ldb, n0,   k0, Bs);
        __syncthreads();
        short8 af[4], bfr[4];
#pragma unroll
        for (int f = 0; f < 4; ++f)
            af[f] = *(const short8*)&As[wm + f * 16 + l16][quad * 8];
#pragma unroll
        for (int f = 0; f < 4; ++f)
            bfr[f] = *(const short8*)&Bs[wn + f * 16 + l16][quad * 8];
#pragma unroll
        for (int fm = 0; fm < 4; ++fm)
#pragma unroll
            for (int fn = 0; fn < 4; ++fn)
                acc[fm][fn] = __builtin_amdgcn_mfma_f32_16x16x32_bf16(
                    af[fm], bfr[fn], acc[fm][fn], 0, 0, 0);
    }
}

// ---------------------------------------------------------------------------
// T1[n][k] = (1 - 0.1*sigmoid(Asc[n][k])) * softmax(Aw[n,:])[k]  (bf16 T-layout)
// ---------------------------------------------------------------------------
__global__ __launch_bounds__(256) void k_weff(
    const float* __restrict__ Aw, const float* __restrict__ Asc,
    unsigned short* __restrict__ T1)
{
    const int n   = blockIdx.x;
    const int tid = threadIdx.x;
    const int lane = tid & 63, wave = tid >> 6;
    float v0 = Aw[(size_t)n * NXX + tid];
    float v1 = Aw[(size_t)n * NXX + 256 + tid];
    __shared__ float sred[4];
    float m = fmaxf(v0, v1);
#pragma unroll
    for (int off = 32; off; off >>= 1) m = fmaxf(m, __shfl_down(m, off));
    if (lane == 0) sred[wave] = m;
    __syncthreads();
    if (tid == 0) sred[0] = fmaxf(fmaxf(sred[0], sred[1]), fmaxf(sred[2], sred[3]));
    __syncthreads();
    const float mm = sred[0];
    __syncthreads();
    float e0 = expf(v0 - mm), e1 = expf(v1 - mm);
    float s = e0 + e1;
#pragma unroll
    for (int off = 32; off; off >>= 1) s += __shfl_down(s, off);
    if (lane == 0) sred[wave] = s;
    __syncthreads();
    if (tid == 0) sred[0] = sred[0] + sred[1] + sred[2] + sred[3];
    __syncthreads();
    const float inv = 1.0f / sred[0];
    float sc0 = 1.0f - 0.1f * (1.0f / (1.0f + expf(-Asc[(size_t)n * NXX + tid])));
    float sc1 = 1.0f - 0.1f * (1.0f / (1.0f + expf(-Asc[(size_t)n * NXX + 256 + tid])));
    unsigned short* out = T1 + (size_t)n * NXX;
    out[tid]       = f2bf(sc0 * e0 * inv);
    out[tid + 256] = f2bf(sc1 * e1 * inv);
}

// ---------------------------------------------------------------------------
// elementwise f32->bf16 prep: Bw (512x128), Ew (512x64), x (256x512 -> G slab 0)
// ---------------------------------------------------------------------------
__global__ __launch_bounds__(256) void k_prep(
    const float* __restrict__ Bw, const float* __restrict__ Ew,
    const float* __restrict__ x,
    unsigned short* __restrict__ Bwb, unsigned short* __restrict__ Ewb,
    unsigned short* __restrict__ G0)
{
    int i = (blockIdx.x * 256 + threadIdx.x) * 4;
    const float* src; unsigned short* dst; int k;
    if (i < 65536)       { src = Bw; dst = Bwb; k = i; }
    else if (i < 98304)  { src = Ew; dst = Ewb; k = i - 65536; }
    else                 { src = x;  dst = G0;  k = i - 98304; }
    float4 v = *(const float4*)(src + k);
    ushort4v h = { f2bf(v.x), f2bf(v.y), f2bf(v.z), f2bf(v.w) };
    *(ushort4v*)(dst + k) = h;
}

// ---------------------------------------------------------------------------
// Power squaring in T-space: slot d = slot a * slot a  (bf16 in/out)
// ---------------------------------------------------------------------------
__global__ __launch_bounds__(256) void k_pow(unsigned short* __restrict__ powb,
                                             int a, int d)
{
    const unsigned short* A = powb + (size_t)a * MS;
    unsigned short*       D = powb + (size_t)d * MS;
    __shared__ unsigned short As[128][LDK];
    __shared__ unsigned short Bs2[128][LDK];
    f32x4 acc[4][4] = {};
    const int row0 = blockIdx.y * 128, n0 = blockIdx.x * 128;
    gemm_mainloop<SK_BF16_NAT, SK_BF16_TRANS>(acc, A, NXX, A, NXX, NXX, row0, n0, As, Bs2);
    const int tid = threadIdx.x;
    const int lane = tid & 63, wave = tid >> 6;
    const int wm = (wave >> 1) * 64, wn = (wave & 1) * 64;
    const int l16 = lane & 15, quad = lane >> 4;
#pragma unroll
    for (int fm = 0; fm < 4; ++fm)
#pragma unroll
        for (int fn = 0; fn < 4; ++fn)
#pragma unroll
            for (int r = 0; r < 4; ++r) {
                int m = row0 + wm + fm * 16 + quad * 4 + r;
                int n = n0 + wn + fn * 16 + l16;
                D[(size_t)m * NXX + n] = f2bf(acc[fm][fn][r]);
            }
}

// ---------------------------------------------------------------------------
// Hillis-Steele prefix step over 32 bf16 chunk-state slabs:
//   c <  s : vdst[c] = vsrc[c]
//   c >= s : vdst[c] = vsrc[c] + vsrc[c-s] @ W^{8s}
// ---------------------------------------------------------------------------
__global__ __launch_bounds__(256) void k_hs(
    const unsigned short* __restrict__ vsrc, unsigned short* __restrict__ vdst,
    const unsigned short* __restrict__ Am, int s)
{
    const int c = blockIdx.z;
    const int row0 = blockIdx.y * 128, n0 = blockIdx.x * 128;
    const int tid = threadIdx.x;
    if (c < s) {
        const unsigned short* sp = vsrc + (size_t)c * BS;
        unsigned short*       dp = vdst + (size_t)c * BS;
#pragma unroll
        for (int i = 0; i < 8; ++i) {
            int idx = tid + i * 256;
            int r = idx >> 4, cc = (idx & 15) << 3;
            *(ushort8*)(dp + (size_t)(row0 + r) * NXX + n0 + cc) =
                *(const ushort8*)(sp + (size_t)(row0 + r) * NXX + n0 + cc);
        }
        return;
    }
    __shared__ unsigned short As[128][LDK];
    __shared__ unsigned short Bs2[128][LDK];
    f32x4 acc[4][4] = {};
    gemm_mainloop<SK_BF16_NAT, SK_BF16_NAT>(acc, vsrc + (size_t)(c - s) * BS, NXX,
                                            Am, NXX, NXX, row0, n0, As, Bs2);
    const int lane = tid & 63, wave = tid >> 6;
    const int wm = (wave >> 1) * 64, wn = (wave & 1) * 64;
    const int l16 = lane & 15, quad = lane >> 4;
    const unsigned short* Cp = vsrc + (size_t)c * BS;
    unsigned short*       Dp = vdst + (size_t)c * BS;
#pragma unroll
    for (int fm = 0; fm < 4; ++fm)
#pragma unroll
        for (int fn = 0; fn < 4; ++fn)
#pragma unroll
            for (int r = 0; r < 4; ++r) {
                int m = row0 + wm + fm * 16 + quad * 4 + r;
                int n = n0 + wn + fn * 16 + l16;
                float v = acc[fm][fn][r] + bf2f(Cp[(size_t)m * NXX + n]);
                Dp[(size_t)m * NXX + n] = f2bf(v);
            }
}

// ---------------------------------------------------------------------------
// Fused per-chunk recurrence. Block = (chunk c, 16 batch rows). State 16x512
// lives in C-frags; LDS round-trip (bf16) provides next step's A-operand.
// Each step also computes inj_t = U[t]@Bw^T + D[t]@Ew^T in-register (K=192).
//  PHASE_C=false: zero-init; writes chunk-end state to Gout slab c+1 (bf16).
//  PHASE_C=true : init state = Vin[c]; writes final X (f32) and Y each step.
// 16-row blocks (grid y=16) -> 512 blocks -> 2 blocks/CU co-resident: the two
// blocks' serial load->MFMA chains interleave on each SIMD (latency hiding).
// ---------------------------------------------------------------------------
template<bool PHASE_C>
__global__ __launch_bounds__(256, 2) void k_scan_fused(
    const float* __restrict__ U, const float* __restrict__ Dm,
    const unsigned short* __restrict__ Bwb, const unsigned short* __restrict__ Ewb,
    const unsigned short* __restrict__ Wt,
    const unsigned short* __restrict__ Vin,
    unsigned short* __restrict__ Gout,
    float* __restrict__ X, float* __restrict__ Y)
{
    const int c   = blockIdx.x;          // chunk 0..31
    const int r0  = blockIdx.y * SR;     // batch-row base (16-row groups)
    const int tid = threadIdx.x;
    const int lane = tid & 63, wave = tid >> 6;
    const int l16 = lane & 15, quad = lane >> 4;

    __shared__ unsigned short Sb[SR][520];   // state bf16 (pad 8 -> +4 bank rot)
    __shared__ unsigned short Ub[SR][136];   // U tile bf16
    __shared__ unsigned short Db[SR][72];    // D tile bf16

    if constexpr (PHASE_C) {
        const unsigned short* vsl = Vin + ((size_t)c * BB + r0) * NXX;
        int row = tid >> 4, col0 = (tid & 15) * 32;
#pragma unroll
        for (int i = 0; i < 4; ++i)
            *(ushort8*)&Sb[row][col0 + i * 8] =
                *(const ushort8*)(vsl + (size_t)row * NXX + col0 + i * 8);
    }

    // per-lane 32-bit element offsets for the 8 n-frags of this wave
    int woff[8], bwoff[8], ewoff[8];
#pragma unroll
    for (int g = 0; g < 8; ++g) {
        int n = wave * 128 + g * 16 + l16;
        woff[g]  = n * NXX + quad * 8;
        bwoff[g] = n * NUU + quad * 8;
        ewoff[g] = n * NDD + quad * 8;
    }

    f32x4 acc[8];

    for (int j = 0; j < CL; ++j) {
        const int t = c * CL + j;
        // ---- stage U (16x128) and D (16x64) f32 -> bf16 into LDS ----
        {
            int row = tid >> 4;
            int uc  = (tid & 15) * 8;
            const float* up = U + ((size_t)t * BB + r0 + row) * NUU + uc;
            float4 a0 = *(const float4*)(up);
            float4 a1 = *(const float4*)(up + 4);
            ushort8 h0 = { f2bf(a0.x), f2bf(a0.y), f2bf(a0.z), f2bf(a0.w),
                           f2bf(a1.x), f2bf(a1.y), f2bf(a1.z), f2bf(a1.w) };
            int dc = (tid & 15) * 4;
            const float* dp = Dm + ((size_t)t * BB + r0 + row) * NDD + dc;
            float4 b0 = *(const float4*)(dp);
            ushort4v hd = { f2bf(b0.x), f2bf(b0.y), f2bf(b0.z), f2bf(b0.w) };
            *(ushort8*)&Ub[row][uc] = h0;
            *(ushort4v*)&Db[row][dc] = hd;
        }
        __syncthreads();   // staging (and prev-step Sb writes) visible

#pragma unroll
        for (int g = 0; g < 8; ++g) acc[g] = (f32x4){0.f, 0.f, 0.f, 0.f};

        // ---- inj: U @ Bw^T  (K=128) ----
#pragma unroll
        for (int kk = 0; kk < 4; ++kk) {
            short8 a0 = *(const short8*)&Ub[l16][kk * 32 + quad * 8];
#pragma unroll
            for (int g = 0; g < 8; ++g) {
                short8 b = *(const short8*)(Bwb + bwoff[g] + kk * 32);
                acc[g] = __builtin_amdgcn_mfma_f32_16x16x32_bf16(a0, b, acc[g], 0, 0, 0);
            }
        }
        // ---- inj: D @ Ew^T  (K=64) ----
#pragma unroll
        for (int kk = 0; kk < 2; ++kk) {
            short8 a0 = *(const short8*)&Db[l16][kk * 32 + quad * 8];
#pragma unroll
            for (int g = 0; g < 8; ++g) {
                short8 b = *(const short8*)(Ewb + ewoff[g] + kk * 32);
                acc[g] = __builtin_amdgcn_mfma_f32_16x16x32_bf16(a0, b, acc[g], 0, 0, 0);
            }
        }
        // ---- state @ W  (K=512) ----
        if (PHASE_C || j > 0) {
#pragma unroll
            for (int kk = 0; kk < 16; ++kk) {
                short8 a0 = *(const short8*)&Sb[l16][kk * 32 + quad * 8];
#pragma unroll
                for (int g = 0; g < 8; ++g) {
                    short8 b = *(const short8*)(Wt + woff[g] + kk * 32);
                    acc[g] = __builtin_amdgcn_mfma_f32_16x16x32_bf16(a0, b, acc[g], 0, 0, 0);
                }
            }
        }
        __syncthreads();   // all reads of Sb done before overwrite

        // ---- write new state (and outputs) ----
#pragma unroll
        for (int g = 0; g < 8; ++g) {
            int n = wave * 128 + g * 16 + l16;
#pragma unroll
            for (int rr = 0; rr < 4; ++rr) {
                int mr = quad * 4 + rr;
                float v = acc[g][rr];
                unsigned short hb = f2bf(v);
                Sb[mr][n] = hb;
                if constexpr (PHASE_C) {
                    X[((size_t)t * BB + r0 + mr) * NXX + n] = v;
                    if (n == NXX - 1) Y[(size_t)t * BB + r0 + mr] = v;
                } else {
                    if (j == CL - 1)
                        Gout[((size_t)(c + 1) * BB + r0 + mr) * NXX + n] = hb;
                }
            }
        }
    }
}

// ---------------------------------------------------------------------------
extern "C" void kernel_launch(void* const* d_in, const int* in_sizes, int n_in,
                              void* d_out, int out_size, void* d_ws, size_t ws_size,
                              hipStream_t stream)
{
    const float* x   = (const float*)d_in[0];
    const float* U   = (const float*)d_in[1];
    const float* Dm  = (const float*)d_in[2];
    const float* Aw  = (const float*)d_in[3];
    const float* Asc = (const float*)d_in[4];
    const float* Bw  = (const float*)d_in[5];
    const float* Ew  = (const float*)d_in[6];

    float* Xout = (float*)d_out;
    float* Yout = Xout + (size_t)TT * BB * NXX;

    // ws layout (bf16): powers slots 0..7 = W^{1,2,4,8,16,32,64,128};
    // Bwb 512x128; Ewb 512x64; G 33 slabs; vA 32; vB 32  (~30 MB total)
    unsigned short* powb = (unsigned short*)d_ws;
    unsigned short* Bwb  = powb + (size_t)8 * MS;
    unsigned short* Ewb  = Bwb + (size_t)NXX * NUU;
    unsigned short* Gbuf = Ewb + (size_t)NXX * NDD;
    unsigned short* vA   = Gbuf + (size_t)(NC + 1) * BS;
    unsigned short* vB   = vA + (size_t)NC * BS;

    dim3 blk(256);

    k_weff<<<dim3(512), blk, 0, stream>>>(Aw, Asc, powb);
    k_prep<<<dim3(224), blk, 0, stream>>>(Bw, Ew, x, Bwb, Ewb, Gbuf);

    // squaring chain: slot i -> slot i+1  (W^1 -> W^2 -> ... -> W^128)
    for (int i = 0; i < 7; ++i)
        k_pow<<<dim3(4, 4), blk, 0, stream>>>(powb, i, i + 1);

    // Pass A: zero-init chunk scans -> chunk-end states into G[1..32]
    k_scan_fused<false><<<dim3(NC, BB / SR), blk, 0, stream>>>(
        U, Dm, Bwb, Ewb, powb, nullptr, Gbuf, nullptr, nullptr);

    // Hillis-Steele prefix over chunk-start states (bf16 slabs)
    k_hs<<<dim3(4, 2, NC), blk, 0, stream>>>(Gbuf, vA, powb + (size_t)3 * MS, 1);
    k_hs<<<dim3(4, 2, NC), blk, 0, stream>>>(vA, vB, powb + (size_t)4 * MS, 2);
    k_hs<<<dim3(4, 2, NC), blk, 0, stream>>>(vB, vA, powb + (size_t)5 * MS, 4);
    k_hs<<<dim3(4, 2, NC), blk, 0, stream>>>(vA, vB, powb + (size_t)6 * MS, 8);
    k_hs<<<dim3(4, 2, NC), blk, 0, stream>>>(vB, vA, powb + (size_t)7 * MS, 16);

    // Pass C: seeded chunk scans -> final X (f32) and Y
    k_scan_fused<true><<<dim3(NC, BB / SR), blk, 0, stream>>>(
        U, Dm, Bwb, Ewb, powb, vA, nullptr, Xout, Yout);
}

// Round 2
// 740.194 us; speedup vs baseline: 2.1508x; 2.1508x over previous
//
#include <hip/hip_runtime.h>
#include <hip/hip_bf16.h>
#include <cstddef>

#define NXX 512
#define NUU 128
#define NDD 64
#define BB  256
#define TT  256
#define CL  8
#define NC  32
#define BS  (BB * NXX)     // one slab in elements (256*512)
#define MS  (NXX * NXX)    // one 512x512 matrix in elements
#define LDK 32             // LDS row stride (bf16) for 128x32 staging tiles

typedef __attribute__((ext_vector_type(8))) short short8;
typedef __attribute__((ext_vector_type(8))) unsigned short ushort8;
typedef __attribute__((ext_vector_type(4))) unsigned short ushort4v;
typedef __attribute__((ext_vector_type(4))) float f32x4;

__device__ __forceinline__ unsigned short f2bf(float f) {
    union { float f; unsigned u; } v; v.f = f;
    unsigned r = v.u + 0x7FFFu + ((v.u >> 16) & 1u);   // RNE
    return (unsigned short)(r >> 16);
}
__device__ __forceinline__ float bf2f(unsigned short h) {
    union { unsigned u; float f; } v; v.u = ((unsigned)h) << 16;
    return v.f;
}

// ---------------------------------------------------------------------------
// 128x128-tile GEMM machinery (used by k_pow / k_hs) — proven in round 2.
// ---------------------------------------------------------------------------
enum StageKind { SK_BF16_NAT, SK_BF16_TRANS };

template<StageKind SK>
__device__ __forceinline__ void stage_tile(const void* src, int ld, int r0, int k0,
                                           unsigned short (*S)[LDK])
{
    const int tid = threadIdx.x;
    if constexpr (SK == SK_BF16_NAT) {
        const unsigned short* s = (const unsigned short*)src;
        const int wave = tid >> 6, lane = tid & 63;
#pragma unroll
        for (int i = 0; i < 2; ++i) {
            int rb = wave * 16 + i * 64;      // wave-uniform row base
            int r  = rb + (lane >> 2);
            int c  = (lane & 3) << 3;
            const unsigned short* g = s + (size_t)(r0 + r) * ld + k0 + c;
            __builtin_amdgcn_global_load_lds(
                (const __attribute__((address_space(1))) void*)g,
                (__attribute__((address_space(3))) void*)&S[rb][0],
                16, 0, 0);
        }
    } else { // SK_BF16_TRANS
        const unsigned short* s = (const unsigned short*)src;
#pragma unroll
        for (int i = 0; i < 2; ++i) {
            int idx = tid + i * 256;
            int m   = idx >> 4;               // 0..31 contraction row
            int c   = (idx & 15) << 3;        // 0..120 output col
            ushort8 v = *(const ushort8*)(s + (size_t)(k0 + m) * ld + r0 + c);
#pragma unroll
            for (int j = 0; j < 8; ++j) S[c + j][m] = v[j];
        }
    }
}

template<StageKind AK, StageKind BK>
__device__ __forceinline__ void gemm_mainloop(
    f32x4 (&acc)[4][4],
    const void* A, int lda, const void* B, int ldb,
    int K, int row0, int n0,
    unsigned short (*As)[LDK], unsigned short (*Bs)[LDK])
{
    const int tid  = threadIdx.x;
    const int lane = tid & 63;
    const int wave = tid >> 6;
    const int wm   = (wave >> 1) * 64;
    const int wn   = (wave & 1) * 64;
    const int l16  = lane & 15;
    const int quad = lane >> 4;

    for (int k0 = 0; k0 < K; k0 += 32) {
        __syncthreads();
        stage_tile<AK>(A, lda, row0, k0, As);
        stage_tile<BK>(B, ldb, n0,   k0, Bs);
        __syncthreads();
        short8 af[4], bfr[4];
#pragma unroll
        for (int f = 0; f < 4; ++f)
            af[f] = *(const short8*)&As[wm + f * 16 + l16][quad * 8];
#pragma unroll
        for (int f = 0; f < 4; ++f)
            bfr[f] = *(const short8*)&Bs[wn + f * 16 + l16][quad * 8];
#pragma unroll
        for (int fm = 0; fm < 4; ++fm)
#pragma unroll
            for (int fn = 0; fn < 4; ++fn)
                acc[fm][fn] = __builtin_amdgcn_mfma_f32_16x16x32_bf16(
                    af[fm], bfr[fn], acc[fm][fn], 0, 0, 0);
    }
}

// ---------------------------------------------------------------------------
// T1[n][k] = (1 - 0.1*sigmoid(Asc[n][k])) * softmax(Aw[n,:])[k]  (bf16 T-layout)
// ---------------------------------------------------------------------------
__global__ __launch_bounds__(256) void k_weff(
    const float* __restrict__ Aw, const float* __restrict__ Asc,
    unsigned short* __restrict__ T1)
{
    const int n   = blockIdx.x;
    const int tid = threadIdx.x;
    const int lane = tid & 63, wave = tid >> 6;
    float v0 = Aw[(size_t)n * NXX + tid];
    float v1 = Aw[(size_t)n * NXX + 256 + tid];
    __shared__ float sred[4];
    float m = fmaxf(v0, v1);
#pragma unroll
    for (int off = 32; off; off >>= 1) m = fmaxf(m, __shfl_down(m, off));
    if (lane == 0) sred[wave] = m;
    __syncthreads();
    if (tid == 0) sred[0] = fmaxf(fmaxf(sred[0], sred[1]), fmaxf(sred[2], sred[3]));
    __syncthreads();
    const float mm = sred[0];
    __syncthreads();
    float e0 = expf(v0 - mm), e1 = expf(v1 - mm);
    float s = e0 + e1;
#pragma unroll
    for (int off = 32; off; off >>= 1) s += __shfl_down(s, off);
    if (lane == 0) sred[wave] = s;
    __syncthreads();
    if (tid == 0) sred[0] = sred[0] + sred[1] + sred[2] + sred[3];
    __syncthreads();
    const float inv = 1.0f / sred[0];
    float sc0 = 1.0f - 0.1f * (1.0f / (1.0f + expf(-Asc[(size_t)n * NXX + tid])));
    float sc1 = 1.0f - 0.1f * (1.0f / (1.0f + expf(-Asc[(size_t)n * NXX + 256 + tid])));
    unsigned short* out = T1 + (size_t)n * NXX;
    out[tid]       = f2bf(sc0 * e0 * inv);
    out[tid + 256] = f2bf(sc1 * e1 * inv);
}

// ---------------------------------------------------------------------------
// elementwise f32->bf16 prep: Bw (512x128), Ew (512x64), x (256x512 -> G slab 0)
// ---------------------------------------------------------------------------
__global__ __launch_bounds__(256) void k_prep(
    const float* __restrict__ Bw, const float* __restrict__ Ew,
    const float* __restrict__ x,
    unsigned short* __restrict__ Bwb, unsigned short* __restrict__ Ewb,
    unsigned short* __restrict__ G0)
{
    int i = (blockIdx.x * 256 + threadIdx.x) * 4;
    const float* src; unsigned short* dst; int k;
    if (i < 65536)       { src = Bw; dst = Bwb; k = i; }
    else if (i < 98304)  { src = Ew; dst = Ewb; k = i - 65536; }
    else                 { src = x;  dst = G0;  k = i - 98304; }
    float4 v = *(const float4*)(src + k);
    ushort4v h = { f2bf(v.x), f2bf(v.y), f2bf(v.z), f2bf(v.w) };
    *(ushort4v*)(dst + k) = h;
}

// ---------------------------------------------------------------------------
// Power squaring in T-space: slot d = slot a * slot a  (bf16 in/out)
// ---------------------------------------------------------------------------
__global__ __launch_bounds__(256) void k_pow(unsigned short* __restrict__ powb,
                                             int a, int d)
{
    const unsigned short* A = powb + (size_t)a * MS;
    unsigned short*       D = powb + (size_t)d * MS;
    __shared__ unsigned short As[128][LDK];
    __shared__ unsigned short Bs2[128][LDK];
    f32x4 acc[4][4] = {};
    const int row0 = blockIdx.y * 128, n0 = blockIdx.x * 128;
    gemm_mainloop<SK_BF16_NAT, SK_BF16_TRANS>(acc, A, NXX, A, NXX, NXX, row0, n0, As, Bs2);
    const int tid = threadIdx.x;
    const int lane = tid & 63, wave = tid >> 6;
    const int wm = (wave >> 1) * 64, wn = (wave & 1) * 64;
    const int l16 = lane & 15, quad = lane >> 4;
#pragma unroll
    for (int fm = 0; fm < 4; ++fm)
#pragma unroll
        for (int fn = 0; fn < 4; ++fn)
#pragma unroll
            for (int r = 0; r < 4; ++r) {
                int m = row0 + wm + fm * 16 + quad * 4 + r;
                int n = n0 + wn + fn * 16 + l16;
                D[(size_t)m * NXX + n] = f2bf(acc[fm][fn][r]);
            }
}

// ---------------------------------------------------------------------------
// Hillis-Steele prefix step over 32 bf16 chunk-state slabs:
//   c <  s : vdst[c] = vsrc[c]
//   c >= s : vdst[c] = vsrc[c] + vsrc[c-s] @ W^{8s}
// ---------------------------------------------------------------------------
__global__ __launch_bounds__(256) void k_hs(
    const unsigned short* __restrict__ vsrc, unsigned short* __restrict__ vdst,
    const unsigned short* __restrict__ Am, int s)
{
    const int c = blockIdx.z;
    const int row0 = blockIdx.y * 128, n0 = blockIdx.x * 128;
    const int tid = threadIdx.x;
    if (c < s) {
        const unsigned short* sp = vsrc + (size_t)c * BS;
        unsigned short*       dp = vdst + (size_t)c * BS;
#pragma unroll
        for (int i = 0; i < 8; ++i) {
            int idx = tid + i * 256;
            int r = idx >> 4, cc = (idx & 15) << 3;
            *(ushort8*)(dp + (size_t)(row0 + r) * NXX + n0 + cc) =
                *(const ushort8*)(sp + (size_t)(row0 + r) * NXX + n0 + cc);
        }
        return;
    }
    __shared__ unsigned short As[128][LDK];
    __shared__ unsigned short Bs2[128][LDK];
    f32x4 acc[4][4] = {};
    gemm_mainloop<SK_BF16_NAT, SK_BF16_NAT>(acc, vsrc + (size_t)(c - s) * BS, NXX,
                                            Am, NXX, NXX, row0, n0, As, Bs2);
    const int lane = tid & 63, wave = tid >> 6;
    const int wm = (wave >> 1) * 64, wn = (wave & 1) * 64;
    const int l16 = lane & 15, quad = lane >> 4;
    const unsigned short* Cp = vsrc + (size_t)c * BS;
    unsigned short*       Dp = vdst + (size_t)c * BS;
#pragma unroll
    for (int fm = 0; fm < 4; ++fm)
#pragma unroll
        for (int fn = 0; fn < 4; ++fn)
#pragma unroll
            for (int r = 0; r < 4; ++r) {
                int m = row0 + wm + fm * 16 + quad * 4 + r;
                int n = n0 + wn + fn * 16 + l16;
                float v = acc[fm][fn][r] + bf2f(Cp[(size_t)m * NXX + n]);
                Dp[(size_t)m * NXX + n] = f2bf(v);
            }
}

// ---------------------------------------------------------------------------
// Fused per-chunk recurrence. Block = (chunk c, 32 batch rows), 1024 threads
// (16 waves, 4 waves/SIMD). Each wave owns 32 output cols (g=2), all 32 rows
// (f=2) -> each 16B W-fragment load feeds 2 MFMAs (same ratio as the proven
// 4-wave version), per-block W traffic unchanged, but 4x the waves/SIMD to
// hide L2/L3 load latency. State 32x512 lives in C-frags; LDS round-trip
// (bf16) provides next step's A-operand. Each step also computes
// inj_t = U[t]@Bw^T + D[t]@Ew^T in-register (K=192).
//  PHASE_C=false: zero-init; writes chunk-end state to Gout slab c+1 (bf16).
//  PHASE_C=true : init state = Vin[c]; writes final X (f32) and Y each step.
// ---------------------------------------------------------------------------
template<bool PHASE_C>
__global__ __launch_bounds__(1024, 4) void k_scan_fused(
    const float* __restrict__ U, const float* __restrict__ Dm,
    const unsigned short* __restrict__ Bwb, const unsigned short* __restrict__ Ewb,
    const unsigned short* __restrict__ Wt,
    const unsigned short* __restrict__ Vin,
    unsigned short* __restrict__ Gout,
    float* __restrict__ X, float* __restrict__ Y)
{
    const int c   = blockIdx.x;          // chunk 0..31
    const int r0  = blockIdx.y * 32;     // batch-row base
    const int tid = threadIdx.x;         // 0..1023
    const int lane = tid & 63, wave = tid >> 6;   // wave 0..15
    const int l16 = lane & 15, quad = lane >> 4;

    __shared__ unsigned short Sb[32][520];   // state bf16 (pad 8 -> +4 bank rot)
    __shared__ unsigned short Ub[32][136];   // U tile bf16
    __shared__ unsigned short Db[32][72];    // D tile bf16

    if constexpr (PHASE_C) {
        const unsigned short* vsl = Vin + ((size_t)c * BB + r0) * NXX;
        int row = tid >> 5, col0 = (tid & 31) * 16;
#pragma unroll
        for (int i = 0; i < 2; ++i)
            *(ushort8*)&Sb[row][col0 + i * 8] =
                *(const ushort8*)(vsl + (size_t)row * NXX + col0 + i * 8);
    }

    // per-lane 32-bit element offsets for the 2 n-frags of this wave
    int woff[2], bwoff[2], ewoff[2];
#pragma unroll
    for (int g = 0; g < 2; ++g) {
        int n = wave * 32 + g * 16 + l16;
        woff[g]  = n * NXX + quad * 8;
        bwoff[g] = n * NUU + quad * 8;
        ewoff[g] = n * NDD + quad * 8;
    }

    f32x4 acc[2][2];

    for (int j = 0; j < CL; ++j) {
        const int t = c * CL + j;
        // ---- stage U (32x128) and D (32x64) f32 -> bf16 into LDS ----
        {
            int row = tid >> 5;               // 0..31
            int uc  = (tid & 31) * 4;         // 4 floats -> 128 cols
            const float* up = U + ((size_t)t * BB + r0 + row) * NUU + uc;
            float4 a0 = *(const float4*)(up);
            ushort4v h0 = { f2bf(a0.x), f2bf(a0.y), f2bf(a0.z), f2bf(a0.w) };
            *(ushort4v*)&Ub[row][uc] = h0;
            int dc = (tid & 31) * 2;          // 2 floats -> 64 cols
            const float* dp = Dm + ((size_t)t * BB + r0 + row) * NDD + dc;
            float2 b0 = *(const float2*)(dp);
            unsigned pk = (unsigned)f2bf(b0.x) | ((unsigned)f2bf(b0.y) << 16);
            *(unsigned*)&Db[row][dc] = pk;
        }
        __syncthreads();   // staging (and prev-step Sb writes) visible

#pragma unroll
        for (int f = 0; f < 2; ++f)
#pragma unroll
            for (int g = 0; g < 2; ++g) acc[f][g] = (f32x4){0.f, 0.f, 0.f, 0.f};

        // ---- inj: U @ Bw^T  (K=128) ----
#pragma unroll
        for (int kk = 0; kk < 4; ++kk) {
            short8 a0 = *(const short8*)&Ub[l16][kk * 32 + quad * 8];
            short8 a1 = *(const short8*)&Ub[16 + l16][kk * 32 + quad * 8];
#pragma unroll
            for (int g = 0; g < 2; ++g) {
                short8 b = *(const short8*)(Bwb + bwoff[g] + kk * 32);
                acc[0][g] = __builtin_amdgcn_mfma_f32_16x16x32_bf16(a0, b, acc[0][g], 0, 0, 0);
                acc[1][g] = __builtin_amdgcn_mfma_f32_16x16x32_bf16(a1, b, acc[1][g], 0, 0, 0);
            }
        }
        // ---- inj: D @ Ew^T  (K=64) ----
#pragma unroll
        for (int kk = 0; kk < 2; ++kk) {
            short8 a0 = *(const short8*)&Db[l16][kk * 32 + quad * 8];
            short8 a1 = *(const short8*)&Db[16 + l16][kk * 32 + quad * 8];
#pragma unroll
            for (int g = 0; g < 2; ++g) {
                short8 b = *(const short8*)(Ewb + ewoff[g] + kk * 32);
                acc[0][g] = __builtin_amdgcn_mfma_f32_16x16x32_bf16(a0, b, acc[0][g], 0, 0, 0);
                acc[1][g] = __builtin_amdgcn_mfma_f32_16x16x32_bf16(a1, b, acc[1][g], 0, 0, 0);
            }
        }
        // ---- state @ W  (K=512) ----
        if (PHASE_C || j > 0) {
#pragma unroll
            for (int kk = 0; kk < 16; ++kk) {
                short8 a0 = *(const short8*)&Sb[l16][kk * 32 + quad * 8];
                short8 a1 = *(const short8*)&Sb[16 + l16][kk * 32 + quad * 8];
#pragma unroll
                for (int g = 0; g < 2; ++g) {
                    short8 b = *(const short8*)(Wt + woff[g] + kk * 32);
                    acc[0][g] = __builtin_amdgcn_mfma_f32_16x16x32_bf16(a0, b, acc[0][g], 0, 0, 0);
                    acc[1][g] = __builtin_amdgcn_mfma_f32_16x16x32_bf16(a1, b, acc[1][g], 0, 0, 0);
                }
            }
        }
        __syncthreads();   // all reads of Sb done before overwrite

        // ---- write new state (and outputs) ----
#pragma unroll
        for (int f = 0; f < 2; ++f)
#pragma unroll
            for (int g = 0; g < 2; ++g) {
                int n = wave * 32 + g * 16 + l16;
#pragma unroll
                for (int rr = 0; rr < 4; ++rr) {
                    int mr = f * 16 + quad * 4 + rr;
                    float v = acc[f][g][rr];
                    unsigned short hb = f2bf(v);
                    Sb[mr][n] = hb;
                    if constexpr (PHASE_C) {
                        X[((size_t)t * BB + r0 + mr) * NXX + n] = v;
                        if (n == NXX - 1) Y[(size_t)t * BB + r0 + mr] = v;
                    } else {
                        if (j == CL - 1)
                            Gout[((size_t)(c + 1) * BB + r0 + mr) * NXX + n] = hb;
                    }
                }
            }
    }
}

// ---------------------------------------------------------------------------
extern "C" void kernel_launch(void* const* d_in, const int* in_sizes, int n_in,
                              void* d_out, int out_size, void* d_ws, size_t ws_size,
                              hipStream_t stream)
{
    const float* x   = (const float*)d_in[0];
    const float* U   = (const float*)d_in[1];
    const float* Dm  = (const float*)d_in[2];
    const float* Aw  = (const float*)d_in[3];
    const float* Asc = (const float*)d_in[4];
    const float* Bw  = (const float*)d_in[5];
    const float* Ew  = (const float*)d_in[6];

    float* Xout = (float*)d_out;
    float* Yout = Xout + (size_t)TT * BB * NXX;

    // ws layout (bf16): powers slots 0..7 = W^{1,2,4,8,16,32,64,128};
    // Bwb 512x128; Ewb 512x64; G 33 slabs; vA 32; vB 32  (~30 MB total)
    unsigned short* powb = (unsigned short*)d_ws;
    unsigned short* Bwb  = powb + (size_t)8 * MS;
    unsigned short* Ewb  = Bwb + (size_t)NXX * NUU;
    unsigned short* Gbuf = Ewb + (size_t)NXX * NDD;
    unsigned short* vA   = Gbuf + (size_t)(NC + 1) * BS;
    unsigned short* vB   = vA + (size_t)NC * BS;

    dim3 blk(256);
    dim3 blkScan(1024);

    k_weff<<<dim3(512), blk, 0, stream>>>(Aw, Asc, powb);
    k_prep<<<dim3(224), blk, 0, stream>>>(Bw, Ew, x, Bwb, Ewb, Gbuf);

    // squaring chain: slot i -> slot i+1  (W^1 -> W^2 -> ... -> W^128)
    for (int i = 0; i < 7; ++i)
        k_pow<<<dim3(4, 4), blk, 0, stream>>>(powb, i, i + 1);

    // Pass A: zero-init chunk scans -> chunk-end states into G[1..32]
    k_scan_fused<false><<<dim3(NC, 8), blkScan, 0, stream>>>(
        U, Dm, Bwb, Ewb, powb, nullptr, Gbuf, nullptr, nullptr);

    // Hillis-Steele prefix over chunk-start states (bf16 slabs)
    k_hs<<<dim3(4, 2, NC), blk, 0, stream>>>(Gbuf, vA, powb + (size_t)3 * MS, 1);
    k_hs<<<dim3(4, 2, NC), blk, 0, stream>>>(vA, vB, powb + (size_t)4 * MS, 2);
    k_hs<<<dim3(4, 2, NC), blk, 0, stream>>>(vB, vA, powb + (size_t)5 * MS, 4);
    k_hs<<<dim3(4, 2, NC), blk, 0, stream>>>(vA, vB, powb + (size_t)6 * MS, 8);
    k_hs<<<dim3(4, 2, NC), blk, 0, stream>>>(vB, vA, powb + (size_t)7 * MS, 16);

    // Pass C: seeded chunk scans -> final X (f32) and Y
    k_scan_fused<true><<<dim3(NC, 8), blkScan, 0, stream>>>(
        U, Dm, Bwb, Ewb, powb, vA, nullptr, Xout, Yout);
}

// Round 4
// 663.575 us; speedup vs baseline: 2.3991x; 1.1155x over previous
//
#include <hip/hip_runtime.h>
#include <hip/hip_bf16.h>
#include <cstddef>

#define NXX 512
#define NUU 128
#define NDD 64
#define BB  256
#define TT  256
#define CL  8
#define NC  32
#define BS  (BB * NXX)     // one slab in elements (256*512)
#define MS  (NXX * NXX)    // one 512x512 matrix in elements
#define LDK 32             // LDS row stride (bf16) for 128x32 staging tiles

typedef __attribute__((ext_vector_type(8))) short short8;
typedef __attribute__((ext_vector_type(8))) unsigned short ushort8;
typedef __attribute__((ext_vector_type(4))) unsigned short ushort4v;
typedef __attribute__((ext_vector_type(4))) float f32x4;

__device__ __forceinline__ unsigned short f2bf(float f) {
    union { float f; unsigned u; } v; v.f = f;
    unsigned r = v.u + 0x7FFFu + ((v.u >> 16) & 1u);   // RNE
    return (unsigned short)(r >> 16);
}
__device__ __forceinline__ float bf2f(unsigned short h) {
    union { unsigned u; float f; } v; v.u = ((unsigned)h) << 16;
    return v.f;
}

// ---------------------------------------------------------------------------
// 128x128-tile GEMM machinery (used by k_mulN / k_hs / k_xcorr).
// ---------------------------------------------------------------------------
enum StageKind { SK_BF16_NAT, SK_BF16_TRANS };

template<StageKind SK>
__device__ __forceinline__ void stage_tile(const void* src, int ld, int r0, int k0,
                                           unsigned short (*S)[LDK])
{
    const int tid = threadIdx.x;
    if constexpr (SK == SK_BF16_NAT) {
        const unsigned short* s = (const unsigned short*)src;
        const int wave = tid >> 6, lane = tid & 63;
#pragma unroll
        for (int i = 0; i < 2; ++i) {
            int rb = wave * 16 + i * 64;      // wave-uniform row base
            int r  = rb + (lane >> 2);
            int c  = (lane & 3) << 3;
            const unsigned short* g = s + (size_t)(r0 + r) * ld + k0 + c;
            __builtin_amdgcn_global_load_lds(
                (const __attribute__((address_space(1))) void*)g,
                (__attribute__((address_space(3))) void*)&S[rb][0],
                16, 0, 0);
        }
    } else { // SK_BF16_TRANS
        const unsigned short* s = (const unsigned short*)src;
#pragma unroll
        for (int i = 0; i < 2; ++i) {
            int idx = tid + i * 256;
            int m   = idx >> 4;               // 0..31 contraction row
            int c   = (idx & 15) << 3;        // 0..120 output col
            ushort8 v = *(const ushort8*)(s + (size_t)(k0 + m) * ld + r0 + c);
#pragma unroll
            for (int j = 0; j < 8; ++j) S[c + j][m] = v[j];
        }
    }
}

template<StageKind AK, StageKind BK>
__device__ __forceinline__ void gemm_mainloop(
    f32x4 (&acc)[4][4],
    const void* A, int lda, const void* B, int ldb,
    int K, int row0, int n0,
    unsigned short (*As)[LDK], unsigned short (*Bs)[LDK])
{
    const int tid  = threadIdx.x;
    const int lane = tid & 63;
    const int wave = tid >> 6;
    const int wm   = (wave >> 1) * 64;
    const int wn   = (wave & 1) * 64;
    const int l16  = lane & 15;
    const int quad = lane >> 4;

    for (int k0 = 0; k0 < K; k0 += 32) {
        __syncthreads();
        stage_tile<AK>(A, lda, row0, k0, As);
        stage_tile<BK>(B, ldb, n0,   k0, Bs);
        __syncthreads();
        short8 af[4], bfr[4];
#pragma unroll
        for (int f = 0; f < 4; ++f)
            af[f] = *(const short8*)&As[wm + f * 16 + l16][quad * 8];
#pragma unroll
        for (int f = 0; f < 4; ++f)
            bfr[f] = *(const short8*)&Bs[wn + f * 16 + l16][quad * 8];
#pragma unroll
        for (int fm = 0; fm < 4; ++fm)
#pragma unroll
            for (int fn = 0; fn < 4; ++fn)
                acc[fm][fn] = __builtin_amdgcn_mfma_f32_16x16x32_bf16(
                    af[fm], bfr[fn], acc[fm][fn], 0, 0, 0);
    }
}

// ---------------------------------------------------------------------------
// T1[n][k] = (1 - 0.1*sigmoid(Asc[n][k])) * softmax(Aw[n,:])[k]  (bf16 T-layout)
// ---------------------------------------------------------------------------
__global__ __launch_bounds__(256) void k_weff(
    const float* __restrict__ Aw, const float* __restrict__ Asc,
    unsigned short* __restrict__ T1)
{
    const int n   = blockIdx.x;
    const int tid = threadIdx.x;
    const int lane = tid & 63, wave = tid >> 6;
    float v0 = Aw[(size_t)n * NXX + tid];
    float v1 = Aw[(size_t)n * NXX + 256 + tid];
    __shared__ float sred[4];
    float m = fmaxf(v0, v1);
#pragma unroll
    for (int off = 32; off; off >>= 1) m = fmaxf(m, __shfl_down(m, off));
    if (lane == 0) sred[wave] = m;
    __syncthreads();
    if (tid == 0) sred[0] = fmaxf(fmaxf(sred[0], sred[1]), fmaxf(sred[2], sred[3]));
    __syncthreads();
    const float mm = sred[0];
    __syncthreads();
    float e0 = expf(v0 - mm), e1 = expf(v1 - mm);
    float s = e0 + e1;
#pragma unroll
    for (int off = 32; off; off >>= 1) s += __shfl_down(s, off);
    if (lane == 0) sred[wave] = s;
    __syncthreads();
    if (tid == 0) sred[0] = sred[0] + sred[1] + sred[2] + sred[3];
    __syncthreads();
    const float inv = 1.0f / sred[0];
    float sc0 = 1.0f - 0.1f * (1.0f / (1.0f + expf(-Asc[(size_t)n * NXX + tid])));
    float sc1 = 1.0f - 0.1f * (1.0f / (1.0f + expf(-Asc[(size_t)n * NXX + 256 + tid])));
    unsigned short* out = T1 + (size_t)n * NXX;
    out[tid]       = f2bf(sc0 * e0 * inv);
    out[tid + 256] = f2bf(sc1 * e1 * inv);
}

// ---------------------------------------------------------------------------
// elementwise f32->bf16 prep: Bw (512x128), Ew (512x64), x (256x512 -> G slab 0)
// ---------------------------------------------------------------------------
__global__ __launch_bounds__(256) void k_prep(
    const float* __restrict__ Bw, const float* __restrict__ Ew,
    const float* __restrict__ x,
    unsigned short* __restrict__ Bwb, unsigned short* __restrict__ Ewb,
    unsigned short* __restrict__ G0)
{
    int i = (blockIdx.x * 256 + threadIdx.x) * 4;
    const float* src; unsigned short* dst; int k;
    if (i < 65536)       { src = Bw; dst = Bwb; k = i; }
    else if (i < 98304)  { src = Ew; dst = Ewb; k = i - 65536; }
    else                 { src = x;  dst = G0;  k = i - 98304; }
    float4 v = *(const float4*)(src + k);
    ushort4v h = { f2bf(v.x), f2bf(v.y), f2bf(v.z), f2bf(v.w) };
    *(ushort4v*)(dst + k) = h;
}

// ---------------------------------------------------------------------------
// Batched power products in T-space: for z = blockIdx.z,
//   slot ds[z] = slot ns[z] (NAT) * slot ts[z] (TRANS)   [= standard product]
// T-space slabs store W^p transposed; T_a * T_b = (W^b W^a)^T = W^(a+b)^T.
// ---------------------------------------------------------------------------
__global__ __launch_bounds__(256) void k_mulN(unsigned short* __restrict__ powb,
                                              int4 ns, int4 ts, int4 ds)
{
    const int z = blockIdx.z;
    const int an = (z == 0) ? ns.x : (z == 1) ? ns.y : (z == 2) ? ns.z : ns.w;
    const int at = (z == 0) ? ts.x : (z == 1) ? ts.y : (z == 2) ? ts.z : ts.w;
    const int ad = (z == 0) ? ds.x : (z == 1) ? ds.y : (z == 2) ? ds.z : ds.w;
    const unsigned short* A = powb + (size_t)an * MS;
    const unsigned short* B = powb + (size_t)at * MS;
    unsigned short*       D = powb + (size_t)ad * MS;
    __shared__ unsigned short As[128][LDK];
    __shared__ unsigned short Bs2[128][LDK];
    f32x4 acc[4][4] = {};
    const int row0 = blockIdx.y * 128, n0 = blockIdx.x * 128;
    gemm_mainloop<SK_BF16_NAT, SK_BF16_TRANS>(acc, A, NXX, B, NXX, NXX, row0, n0, As, Bs2);
    const int tid = threadIdx.x;
    const int lane = tid & 63, wave = tid >> 6;
    const int wm = (wave >> 1) * 64, wn = (wave & 1) * 64;
    const int l16 = lane & 15, quad = lane >> 4;
#pragma unroll
    for (int fm = 0; fm < 4; ++fm)
#pragma unroll
        for (int fn = 0; fn < 4; ++fn)
#pragma unroll
            for (int r = 0; r < 4; ++r) {
                int m = row0 + wm + fm * 16 + quad * 4 + r;
                int n = n0 + wn + fn * 16 + l16;
                D[(size_t)m * NXX + n] = f2bf(acc[fm][fn][r]);
            }
}

// ---------------------------------------------------------------------------
// Hillis-Steele prefix step over 32 bf16 chunk-state slabs:
//   c <  s : vdst[c] = vsrc[c]
//   c >= s : vdst[c] = vsrc[c] + vsrc[c-s] @ W^{8s}
// ---------------------------------------------------------------------------
__global__ __launch_bounds__(256) void k_hs(
    const unsigned short* __restrict__ vsrc, unsigned short* __restrict__ vdst,
    const unsigned short* __restrict__ Am, int s)
{
    const int c = blockIdx.z;
    const int row0 = blockIdx.y * 128, n0 = blockIdx.x * 128;
    const int tid = threadIdx.x;
    if (c < s) {
        const unsigned short* sp = vsrc + (size_t)c * BS;
        unsigned short*       dp = vdst + (size_t)c * BS;
#pragma unroll
        for (int i = 0; i < 8; ++i) {
            int idx = tid + i * 256;
            int r = idx >> 4, cc = (idx & 15) << 3;
            *(ushort8*)(dp + (size_t)(row0 + r) * NXX + n0 + cc) =
                *(const ushort8*)(sp + (size_t)(row0 + r) * NXX + n0 + cc);
        }
        return;
    }
    __shared__ unsigned short As[128][LDK];
    __shared__ unsigned short Bs2[128][LDK];
    f32x4 acc[4][4] = {};
    gemm_mainloop<SK_BF16_NAT, SK_BF16_NAT>(acc, vsrc + (size_t)(c - s) * BS, NXX,
                                            Am, NXX, NXX, row0, n0, As, Bs2);
    const int lane = tid & 63, wave = tid >> 6;
    const int wm = (wave >> 1) * 64, wn = (wave & 1) * 64;
    const int l16 = lane & 15, quad = lane >> 4;
    const unsigned short* Cp = vsrc + (size_t)c * BS;
    unsigned short*       Dp = vdst + (size_t)c * BS;
#pragma unroll
    for (int fm = 0; fm < 4; ++fm)
#pragma unroll
        for (int fn = 0; fn < 4; ++fn)
#pragma unroll
            for (int r = 0; r < 4; ++r) {
                int m = row0 + wm + fm * 16 + quad * 4 + r;
                int n = n0 + wn + fn * 16 + l16;
                float v = acc[fm][fn][r] + bf2f(Cp[(size_t)m * NXX + n]);
                Dp[(size_t)m * NXX + n] = f2bf(v);
            }
}

// ---------------------------------------------------------------------------
// Seed-correction GEMM (replaces serial pass C):
//   t = blockIdx.z, c = t/8, j = t%8:  X[t] += vA[c] @ W^{j+1};  Y = X[:,:,511]
// 2048 independent 128x128x512 tiles -> full GEMM parallelism, no scan chain.
// ---------------------------------------------------------------------------
__global__ __launch_bounds__(256) void k_xcorr(
    const unsigned short* __restrict__ vA, const unsigned short* __restrict__ powb,
    float* __restrict__ X, float* __restrict__ Y)
{
    const int t = blockIdx.z;
    const int c = t >> 3, j = t & 7;
    const int row0 = blockIdx.y * 128, n0 = blockIdx.x * 128;
    __shared__ unsigned short As[128][LDK];
    __shared__ unsigned short Bs2[128][LDK];
    f32x4 acc[4][4] = {};
    gemm_mainloop<SK_BF16_NAT, SK_BF16_NAT>(acc, vA + (size_t)c * BS, NXX,
                                            powb + (size_t)j * MS, NXX, NXX,
                                            row0, n0, As, Bs2);
    const int tid = threadIdx.x;
    const int lane = tid & 63, wave = tid >> 6;
    const int wm = (wave >> 1) * 64, wn = (wave & 1) * 64;
    const int l16 = lane & 15, quad = lane >> 4;
    float* Xt = X + (size_t)t * BB * NXX;
#pragma unroll
    for (int fm = 0; fm < 4; ++fm)
#pragma unroll
        for (int fn = 0; fn < 4; ++fn)
#pragma unroll
            for (int r = 0; r < 4; ++r) {
                int m = row0 + wm + fm * 16 + quad * 4 + r;
                int n = n0 + wn + fn * 16 + l16;
                float v = acc[fm][fn][r] + Xt[(size_t)m * NXX + n];
                Xt[(size_t)m * NXX + n] = v;
                if (n == NXX - 1) Y[(size_t)t * BB + m] = v;
            }
}

// ---------------------------------------------------------------------------
// Pass A: fused per-chunk zero-init recurrence. Block = (chunk c, 32 rows),
// 1024 threads (16 waves). Writes every step's state to X (f32, = zero-init
// scan result xA) and the chunk-end state to Gout slab c+1 (bf16).
// ---------------------------------------------------------------------------
__global__ __launch_bounds__(1024, 4) void k_scanA(
    const float* __restrict__ U, const float* __restrict__ Dm,
    const unsigned short* __restrict__ Bwb, const unsigned short* __restrict__ Ewb,
    const unsigned short* __restrict__ Wt,
    unsigned short* __restrict__ Gout,
    float* __restrict__ X)
{
    const int c   = blockIdx.x;          // chunk 0..31
    const int r0  = blockIdx.y * 32;     // batch-row base
    const int tid = threadIdx.x;         // 0..1023
    const int lane = tid & 63, wave = tid >> 6;   // wave 0..15
    const int l16 = lane & 15, quad = lane >> 4;

    __shared__ unsigned short Sb[32][520];   // state bf16 (pad 8 -> +4 bank rot)
    __shared__ unsigned short Ub[32][136];   // U tile bf16
    __shared__ unsigned short Db[32][72];    // D tile bf16

    // per-lane 32-bit element offsets for the 2 n-frags of this wave
    int woff[2], bwoff[2], ewoff[2];
#pragma unroll
    for (int g = 0; g < 2; ++g) {
        int n = wave * 32 + g * 16 + l16;
        woff[g]  = n * NXX + quad * 8;
        bwoff[g] = n * NUU + quad * 8;
        ewoff[g] = n * NDD + quad * 8;
    }

    f32x4 acc[2][2];

    for (int j = 0; j < CL; ++j) {
        const int t = c * CL + j;
        // ---- stage U (32x128) and D (32x64) f32 -> bf16 into LDS ----
        {
            int row = tid >> 5;               // 0..31
            int uc  = (tid & 31) * 4;         // 4 floats -> 128 cols
            const float* up = U + ((size_t)t * BB + r0 + row) * NUU + uc;
            float4 a0 = *(const float4*)(up);
            ushort4v h0 = { f2bf(a0.x), f2bf(a0.y), f2bf(a0.z), f2bf(a0.w) };
            *(ushort4v*)&Ub[row][uc] = h0;
            int dc = (tid & 31) * 2;          // 2 floats -> 64 cols
            const float* dp = Dm + ((size_t)t * BB + r0 + row) * NDD + dc;
            float2 b0 = *(const float2*)(dp);
            unsigned pk = (unsigned)f2bf(b0.x) | ((unsigned)f2bf(b0.y) << 16);
            *(unsigned*)&Db[row][dc] = pk;
        }
        __syncthreads();   // staging (and prev-step Sb writes) visible

#pragma unroll
        for (int f = 0; f < 2; ++f)
#pragma unroll
            for (int g = 0; g < 2; ++g) acc[f][g] = (f32x4){0.f, 0.f, 0.f, 0.f};

        // ---- inj: U @ Bw^T  (K=128) ----
#pragma unroll
        for (int kk = 0; kk < 4; ++kk) {
            short8 a0 = *(const short8*)&Ub[l16][kk * 32 + quad * 8];
            short8 a1 = *(const short8*)&Ub[16 + l16][kk * 32 + quad * 8];
#pragma unroll
            for (int g = 0; g < 2; ++g) {
                short8 b = *(const short8*)(Bwb + bwoff[g] + kk * 32);
                acc[0][g] = __builtin_amdgcn_mfma_f32_16x16x32_bf16(a0, b, acc[0][g], 0, 0, 0);
                acc[1][g] = __builtin_amdgcn_mfma_f32_16x16x32_bf16(a1, b, acc[1][g], 0, 0, 0);
            }
        }
        // ---- inj: D @ Ew^T  (K=64) ----
#pragma unroll
        for (int kk = 0; kk < 2; ++kk) {
            short8 a0 = *(const short8*)&Db[l16][kk * 32 + quad * 8];
            short8 a1 = *(const short8*)&Db[16 + l16][kk * 32 + quad * 8];
#pragma unroll
            for (int g = 0; g < 2; ++g) {
                short8 b = *(const short8*)(Ewb + ewoff[g] + kk * 32);
                acc[0][g] = __builtin_amdgcn_mfma_f32_16x16x32_bf16(a0, b, acc[0][g], 0, 0, 0);
                acc[1][g] = __builtin_amdgcn_mfma_f32_16x16x32_bf16(a1, b, acc[1][g], 0, 0, 0);
            }
        }
        // ---- state @ W  (K=512) ----
        if (j > 0) {
#pragma unroll
            for (int kk = 0; kk < 16; ++kk) {
                short8 a0 = *(const short8*)&Sb[l16][kk * 32 + quad * 8];
                short8 a1 = *(const short8*)&Sb[16 + l16][kk * 32 + quad * 8];
#pragma unroll
                for (int g = 0; g < 2; ++g) {
                    short8 b = *(const short8*)(Wt + woff[g] + kk * 32);
                    acc[0][g] = __builtin_amdgcn_mfma_f32_16x16x32_bf16(a0, b, acc[0][g], 0, 0, 0);
                    acc[1][g] = __builtin_amdgcn_mfma_f32_16x16x32_bf16(a1, b, acc[1][g], 0, 0, 0);
                }
            }
        }
        __syncthreads();   // all reads of Sb done before overwrite

        // ---- write new state + xA (f32) ----
#pragma unroll
        for (int f = 0; f < 2; ++f)
#pragma unroll
            for (int g = 0; g < 2; ++g) {
                int n = wave * 32 + g * 16 + l16;
#pragma unroll
                for (int rr = 0; rr < 4; ++rr) {
                    int mr = f * 16 + quad * 4 + rr;
                    float v = acc[f][g][rr];
                    unsigned short hb = f2bf(v);
                    Sb[mr][n] = hb;
                    X[((size_t)t * BB + r0 + mr) * NXX + n] = v;
                    if (j == CL - 1)
                        Gout[((size_t)(c + 1) * BB + r0 + mr) * NXX + n] = hb;
                }
            }
    }
}

// ---------------------------------------------------------------------------
extern "C" void kernel_launch(void* const* d_in, const int* in_sizes, int n_in,
                              void* d_out, int out_size, void* d_ws, size_t ws_size,
                              hipStream_t stream)
{
    const float* x   = (const float*)d_in[0];
    const float* U   = (const float*)d_in[1];
    const float* Dm  = (const float*)d_in[2];
    const float* Aw  = (const float*)d_in[3];
    const float* Asc = (const float*)d_in[4];
    const float* Bw  = (const float*)d_in[5];
    const float* Ew  = (const float*)d_in[6];

    float* Xout = (float*)d_out;
    float* Yout = Xout + (size_t)TT * BB * NXX;

    // ws layout (bf16): power slots 0..7 = W^{1..8}, 8..11 = W^{16,32,64,128};
    // Bwb 512x128; Ewb 512x64; G 33 slabs; vA 32; vB 32  (~32 MB total)
    unsigned short* powb = (unsigned short*)d_ws;
    unsigned short* Bwb  = powb + (size_t)12 * MS;
    unsigned short* Ewb  = Bwb + (size_t)NXX * NUU;
    unsigned short* Gbuf = Ewb + (size_t)NXX * NDD;
    unsigned short* vA   = Gbuf + (size_t)(NC + 1) * BS;
    unsigned short* vB   = vA + (size_t)NC * BS;

    dim3 blk(256);
    dim3 blkScan(1024);

    k_weff<<<dim3(512), blk, 0, stream>>>(Aw, Asc, powb);
    k_prep<<<dim3(224), blk, 0, stream>>>(Bw, Ew, x, Bwb, Ewb, Gbuf);

    // power products (T-space; slot p-1 = W^p for p=1..8, then W^{16,32,64,128})
    // level 1: W^2 = W*W
    k_mulN<<<dim3(4, 4, 1), blk, 0, stream>>>(powb,
        make_int4(0, 0, 0, 0), make_int4(0, 0, 0, 0), make_int4(1, 0, 0, 0));
    // level 2: W^3 = W^2*W, W^4 = W^2*W^2
    k_mulN<<<dim3(4, 4, 2), blk, 0, stream>>>(powb,
        make_int4(1, 1, 0, 0), make_int4(0, 1, 0, 0), make_int4(2, 3, 0, 0));
    // level 3: W^5..W^8 all from W^4
    k_mulN<<<dim3(4, 4, 4), blk, 0, stream>>>(powb,
        make_int4(3, 3, 3, 3), make_int4(0, 1, 2, 3), make_int4(4, 5, 6, 7));
    // levels 4..7: W^16, W^32, W^64, W^128 by squaring
    k_mulN<<<dim3(4, 4, 1), blk, 0, stream>>>(powb,
        make_int4(7, 0, 0, 0), make_int4(7, 0, 0, 0), make_int4(8, 0, 0, 0));
    k_mulN<<<dim3(4, 4, 1), blk, 0, stream>>>(powb,
        make_int4(8, 0, 0, 0), make_int4(8, 0, 0, 0), make_int4(9, 0, 0, 0));
    k_mulN<<<dim3(4, 4, 1), blk, 0, stream>>>(powb,
        make_int4(9, 0, 0, 0), make_int4(9, 0, 0, 0), make_int4(10, 0, 0, 0));
    k_mulN<<<dim3(4, 4, 1), blk, 0, stream>>>(powb,
        make_int4(10, 0, 0, 0), make_int4(10, 0, 0, 0), make_int4(11, 0, 0, 0));

    // Pass A: zero-init chunk scans -> xA into X (f32), chunk-ends into G[1..32]
    k_scanA<<<dim3(NC, 8), blkScan, 0, stream>>>(
        U, Dm, Bwb, Ewb, powb, Gbuf, Xout);

    // Hillis-Steele prefix over chunk-start states (bf16 slabs)
    k_hs<<<dim3(4, 2, NC), blk, 0, stream>>>(Gbuf, vA, powb + (size_t)7 * MS, 1);
    k_hs<<<dim3(4, 2, NC), blk, 0, stream>>>(vA, vB, powb + (size_t)8 * MS, 2);
    k_hs<<<dim3(4, 2, NC), blk, 0, stream>>>(vB, vA, powb + (size_t)9 * MS, 4);
    k_hs<<<dim3(4, 2, NC), blk, 0, stream>>>(vA, vB, powb + (size_t)10 * MS, 8);
    k_hs<<<dim3(4, 2, NC), blk, 0, stream>>>(vB, vA, powb + (size_t)11 * MS, 16);

    // Seed-correction GEMM: X[t] += vA[t/8] @ W^{(t%8)+1}; writes Y
    k_xcorr<<<dim3(4, 2, TT), blk, 0, stream>>>(vA, powb, Xout, Yout);
}

// Round 5
// 611.383 us; speedup vs baseline: 2.6039x; 1.0854x over previous
//
#include <hip/hip_runtime.h>
#include <hip/hip_bf16.h>
#include <cstddef>

#define NXX 512
#define NUU 128
#define NDD 64
#define BB  256
#define TT  256
#define CL  8
#define NC  32
#define BS  (BB * NXX)     // one slab in elements (256*512)
#define MS  (NXX * NXX)    // one 512x512 matrix in elements
#define LDK 32             // LDS row stride (bf16) for 128x32 staging tiles

typedef __attribute__((ext_vector_type(8))) short short8;
typedef __attribute__((ext_vector_type(8))) unsigned short ushort8;
typedef __attribute__((ext_vector_type(4))) unsigned short ushort4v;
typedef __attribute__((ext_vector_type(4))) float f32x4;

__device__ __forceinline__ unsigned short f2bf(float f) {
    union { float f; unsigned u; } v; v.f = f;
    unsigned r = v.u + 0x7FFFu + ((v.u >> 16) & 1u);   // RNE
    return (unsigned short)(r >> 16);
}
__device__ __forceinline__ float bf2f(unsigned short h) {
    union { unsigned u; float f; } v; v.u = ((unsigned)h) << 16;
    return v.f;
}

// ---------------------------------------------------------------------------
// 2-phase double-buffered 128x128-tile GEMM machinery (mulN / hs / xcorr).
// One __syncthreads per k-step; stage of tile k+1 issued BEFORE compute of
// tile k so the barrier's vmcnt(0) drain lands after ~1000cy of MFMA work.
// ---------------------------------------------------------------------------
enum StageKind { SK_BF16_NAT, SK_BF16_TRANS };

__device__ __forceinline__ void stage_nat(const unsigned short* s, int ld, int r0,
                                          int k0, unsigned short (*S)[LDK])
{
    const int tid = threadIdx.x;
    const int wave = tid >> 6, lane = tid & 63;
#pragma unroll
    for (int i = 0; i < 2; ++i) {
        int rb = wave * 16 + i * 64;      // wave-uniform row base
        int r  = rb + (lane >> 2);
        int c  = (lane & 3) << 3;
        const unsigned short* g = s + (size_t)(r0 + r) * ld + k0 + c;
        __builtin_amdgcn_global_load_lds(
            (const __attribute__((address_space(1))) void*)g,
            (__attribute__((address_space(3))) void*)&S[rb][0],
            16, 0, 0);
    }
}
__device__ __forceinline__ ushort8 ldT(const unsigned short* s, int ld, int r0,
                                       int k0, int i)
{
    int idx = threadIdx.x + i * 256;
    int m   = idx >> 4;                   // 0..31 contraction row
    int c   = (idx & 15) << 3;            // 0..120 output col
    return *(const ushort8*)(s + (size_t)(k0 + m) * ld + r0 + c);
}
__device__ __forceinline__ void wrT(ushort8 v, int i, unsigned short (*S)[LDK])
{
    int idx = threadIdx.x + i * 256;
    int m   = idx >> 4;
    int c   = (idx & 15) << 3;
#pragma unroll
    for (int j = 0; j < 8; ++j) S[c + j][m] = v[j];
}

template<StageKind AK, StageKind BK>
__device__ __forceinline__ void gemm2_mainloop(
    f32x4 (&acc)[4][4],
    const void* A, int lda, const void* B, int ldb,
    int K, int row0, int n0,
    unsigned short (*As)[128][LDK], unsigned short (*Bs)[128][LDK])
{
    const int tid  = threadIdx.x;
    const int lane = tid & 63;
    const int wave = tid >> 6;
    const int wm   = (wave >> 1) * 64;
    const int wn   = (wave & 1) * 64;
    const int l16  = lane & 15;
    const int quad = lane >> 4;
    const unsigned short* Ap = (const unsigned short*)A;
    const unsigned short* Bp = (const unsigned short*)B;
    const int NT = K >> 5;

    // prologue: stage k0=0 into buffer 0
    if constexpr (AK == SK_BF16_NAT) stage_nat(Ap, lda, row0, 0, As[0]);
    else { wrT(ldT(Ap, lda, row0, 0, 0), 0, As[0]); wrT(ldT(Ap, lda, row0, 0, 1), 1, As[0]); }
    if constexpr (BK == SK_BF16_NAT) stage_nat(Bp, ldb, n0, 0, Bs[0]);
    else { wrT(ldT(Bp, ldb, n0, 0, 0), 0, Bs[0]); wrT(ldT(Bp, ldb, n0, 0, 1), 1, Bs[0]); }
    __syncthreads();

    for (int t = 0; t < NT; ++t) {
        const int cur = t & 1, nxt = cur ^ 1;
        const int k1  = (t + 1) << 5;
        ushort8 ta0, ta1, tb0, tb1;
        if (t + 1 < NT) {
            if constexpr (AK == SK_BF16_NAT) stage_nat(Ap, lda, row0, k1, As[nxt]);
            else { ta0 = ldT(Ap, lda, row0, k1, 0); ta1 = ldT(Ap, lda, row0, k1, 1); }
            if constexpr (BK == SK_BF16_NAT) stage_nat(Bp, ldb, n0, k1, Bs[nxt]);
            else { tb0 = ldT(Bp, ldb, n0, k1, 0); tb1 = ldT(Bp, ldb, n0, k1, 1); }
        }
        short8 af[4], bfr[4];
#pragma unroll
        for (int f = 0; f < 4; ++f)
            af[f] = *(const short8*)&As[cur][wm + f * 16 + l16][quad * 8];
#pragma unroll
        for (int f = 0; f < 4; ++f)
            bfr[f] = *(const short8*)&Bs[cur][wn + f * 16 + l16][quad * 8];
#pragma unroll
        for (int fm = 0; fm < 4; ++fm)
#pragma unroll
            for (int fn = 0; fn < 4; ++fn)
                acc[fm][fn] = __builtin_amdgcn_mfma_f32_16x16x32_bf16(
                    af[fm], bfr[fn], acc[fm][fn], 0, 0, 0);
        if (t + 1 < NT) {
            if constexpr (AK == SK_BF16_TRANS) { wrT(ta0, 0, As[nxt]); wrT(ta1, 1, As[nxt]); }
            if constexpr (BK == SK_BF16_TRANS) { wrT(tb0, 0, Bs[nxt]); wrT(tb1, 1, Bs[nxt]); }
        }
        __syncthreads();   // drains next-tile staging (issued ~1000cy ago) + aligns waves
    }
}

// ---------------------------------------------------------------------------
// T1[n][k] = (1 - 0.1*sigmoid(Asc[n][k])) * softmax(Aw[n,:])[k]  (bf16 T-layout)
// ---------------------------------------------------------------------------
__global__ __launch_bounds__(256) void k_weff(
    const float* __restrict__ Aw, const float* __restrict__ Asc,
    unsigned short* __restrict__ T1)
{
    const int n   = blockIdx.x;
    const int tid = threadIdx.x;
    const int lane = tid & 63, wave = tid >> 6;
    float v0 = Aw[(size_t)n * NXX + tid];
    float v1 = Aw[(size_t)n * NXX + 256 + tid];
    __shared__ float sred[4];
    float m = fmaxf(v0, v1);
#pragma unroll
    for (int off = 32; off; off >>= 1) m = fmaxf(m, __shfl_down(m, off));
    if (lane == 0) sred[wave] = m;
    __syncthreads();
    if (tid == 0) sred[0] = fmaxf(fmaxf(sred[0], sred[1]), fmaxf(sred[2], sred[3]));
    __syncthreads();
    const float mm = sred[0];
    __syncthreads();
    float e0 = expf(v0 - mm), e1 = expf(v1 - mm);
    float s = e0 + e1;
#pragma unroll
    for (int off = 32; off; off >>= 1) s += __shfl_down(s, off);
    if (lane == 0) sred[wave] = s;
    __syncthreads();
    if (tid == 0) sred[0] = sred[0] + sred[1] + sred[2] + sred[3];
    __syncthreads();
    const float inv = 1.0f / sred[0];
    float sc0 = 1.0f - 0.1f * (1.0f / (1.0f + expf(-Asc[(size_t)n * NXX + tid])));
    float sc1 = 1.0f - 0.1f * (1.0f / (1.0f + expf(-Asc[(size_t)n * NXX + 256 + tid])));
    unsigned short* out = T1 + (size_t)n * NXX;
    out[tid]       = f2bf(sc0 * e0 * inv);
    out[tid + 256] = f2bf(sc1 * e1 * inv);
}

// ---------------------------------------------------------------------------
// elementwise f32->bf16 prep: Bw (512x128), Ew (512x64), x (256x512 -> G slab 0)
// ---------------------------------------------------------------------------
__global__ __launch_bounds__(256) void k_prep(
    const float* __restrict__ Bw, const float* __restrict__ Ew,
    const float* __restrict__ x,
    unsigned short* __restrict__ Bwb, unsigned short* __restrict__ Ewb,
    unsigned short* __restrict__ G0)
{
    int i = (blockIdx.x * 256 + threadIdx.x) * 4;
    const float* src; unsigned short* dst; int k;
    if (i < 65536)       { src = Bw; dst = Bwb; k = i; }
    else if (i < 98304)  { src = Ew; dst = Ewb; k = i - 65536; }
    else                 { src = x;  dst = G0;  k = i - 98304; }
    float4 v = *(const float4*)(src + k);
    ushort4v h = { f2bf(v.x), f2bf(v.y), f2bf(v.z), f2bf(v.w) };
    *(ushort4v*)(dst + k) = h;
}

// ---------------------------------------------------------------------------
// Batched power products in T-space: for z = blockIdx.z,
//   slot ds[z] = slot ns[z] (NAT) * slot ts[z] (TRANS)
// T-space product of stored layouts = T_{a+b} (powers commute).
// ---------------------------------------------------------------------------
__global__ __launch_bounds__(256) void k_mulN(unsigned short* __restrict__ powb,
                                              int4 ns, int4 ts, int4 ds)
{
    const int z = blockIdx.z;
    const int an = (z == 0) ? ns.x : (z == 1) ? ns.y : (z == 2) ? ns.z : ns.w;
    const int at = (z == 0) ? ts.x : (z == 1) ? ts.y : (z == 2) ? ts.z : ts.w;
    const int ad = (z == 0) ? ds.x : (z == 1) ? ds.y : (z == 2) ? ds.z : ds.w;
    const unsigned short* A = powb + (size_t)an * MS;
    const unsigned short* B = powb + (size_t)at * MS;
    unsigned short*       D = powb + (size_t)ad * MS;
    __shared__ unsigned short As[2][128][LDK];
    __shared__ unsigned short Bs2[2][128][LDK];
    f32x4 acc[4][4] = {};
    const int row0 = blockIdx.y * 128, n0 = blockIdx.x * 128;
    gemm2_mainloop<SK_BF16_NAT, SK_BF16_TRANS>(acc, A, NXX, B, NXX, NXX, row0, n0, As, Bs2);
    const int tid = threadIdx.x;
    const int lane = tid & 63, wave = tid >> 6;
    const int wm = (wave >> 1) * 64, wn = (wave & 1) * 64;
    const int l16 = lane & 15, quad = lane >> 4;
#pragma unroll
    for (int fm = 0; fm < 4; ++fm)
#pragma unroll
        for (int fn = 0; fn < 4; ++fn)
#pragma unroll
            for (int r = 0; r < 4; ++r) {
                int m = row0 + wm + fm * 16 + quad * 4 + r;
                int n = n0 + wn + fn * 16 + l16;
                D[(size_t)m * NXX + n] = f2bf(acc[fm][fn][r]);
            }
}

// ---------------------------------------------------------------------------
// Fused Hillis-Steele level + piggybacked power squaring.
//   z <  NC: HS slab z:  c<s -> copy; else vdst[c] = vsrc[c] + vsrc[c-s]@W^{8s}
//   z >= NC: squaring tile of T[sqd] = T[sqa]*T[sqa]   (consumed next launch)
// ---------------------------------------------------------------------------
__global__ __launch_bounds__(256) void k_hs_sq(
    const unsigned short* __restrict__ vsrc, unsigned short* __restrict__ vdst,
    const unsigned short* __restrict__ Am, int s,
    unsigned short* __restrict__ powb, int sqa, int sqd)
{
    const int z = blockIdx.z;
    const int tid = threadIdx.x;
    __shared__ unsigned short As[2][128][LDK];
    __shared__ unsigned short Bs2[2][128][LDK];
    const int lane = tid & 63, wave = tid >> 6;
    const int wm = (wave >> 1) * 64, wn = (wave & 1) * 64;
    const int l16 = lane & 15, quad = lane >> 4;

    if (z >= NC) {
        // squaring tile: row0 in {0,128,256,384} via (y + 2*(z-NC))
        const unsigned short* Aq = powb + (size_t)sqa * MS;
        unsigned short*       Dq = powb + (size_t)sqd * MS;
        const int row0 = (blockIdx.y + 2 * (z - NC)) * 128;
        const int n0   = blockIdx.x * 128;
        f32x4 acc[4][4] = {};
        gemm2_mainloop<SK_BF16_NAT, SK_BF16_TRANS>(acc, Aq, NXX, Aq, NXX, NXX, row0, n0, As, Bs2);
#pragma unroll
        for (int fm = 0; fm < 4; ++fm)
#pragma unroll
            for (int fn = 0; fn < 4; ++fn)
#pragma unroll
                for (int r = 0; r < 4; ++r) {
                    int m = row0 + wm + fm * 16 + quad * 4 + r;
                    int n = n0 + wn + fn * 16 + l16;
                    Dq[(size_t)m * NXX + n] = f2bf(acc[fm][fn][r]);
                }
        return;
    }

    const int c = z;
    const int row0 = blockIdx.y * 128, n0 = blockIdx.x * 128;
    if (c < s) {
        const unsigned short* sp = vsrc + (size_t)c * BS;
        unsigned short*       dp = vdst + (size_t)c * BS;
#pragma unroll
        for (int i = 0; i < 8; ++i) {
            int idx = tid + i * 256;
            int r = idx >> 4, cc = (idx & 15) << 3;
            *(ushort8*)(dp + (size_t)(row0 + r) * NXX + n0 + cc) =
                *(const ushort8*)(sp + (size_t)(row0 + r) * NXX + n0 + cc);
        }
        return;
    }
    f32x4 acc[4][4] = {};
    gemm2_mainloop<SK_BF16_NAT, SK_BF16_NAT>(acc, vsrc + (size_t)(c - s) * BS, NXX,
                                             Am, NXX, NXX, row0, n0, As, Bs2);
    const unsigned short* Cp = vsrc + (size_t)c * BS;
    unsigned short*       Dp = vdst + (size_t)c * BS;
#pragma unroll
    for (int fm = 0; fm < 4; ++fm)
#pragma unroll
        for (int fn = 0; fn < 4; ++fn)
#pragma unroll
            for (int r = 0; r < 4; ++r) {
                int m = row0 + wm + fm * 16 + quad * 4 + r;
                int n = n0 + wn + fn * 16 + l16;
                float v = acc[fm][fn][r] + bf2f(Cp[(size_t)m * NXX + n]);
                Dp[(size_t)m * NXX + n] = f2bf(v);
            }
}

// ---------------------------------------------------------------------------
// Seed-correction GEMM (replaces serial pass C):
//   t = blockIdx.z, c = t/8, j = t%8:  X[t] += vA[c] @ W^{j+1};  Y = X[:,:,511]
// ---------------------------------------------------------------------------
__global__ __launch_bounds__(256) void k_xcorr(
    const unsigned short* __restrict__ vA, const unsigned short* __restrict__ powb,
    float* __restrict__ X, float* __restrict__ Y)
{
    const int t = blockIdx.z;
    const int c = t >> 3, j = t & 7;
    const int row0 = blockIdx.y * 128, n0 = blockIdx.x * 128;
    __shared__ unsigned short As[2][128][LDK];
    __shared__ unsigned short Bs2[2][128][LDK];
    f32x4 acc[4][4] = {};
    gemm2_mainloop<SK_BF16_NAT, SK_BF16_NAT>(acc, vA + (size_t)c * BS, NXX,
                                             powb + (size_t)j * MS, NXX, NXX,
                                             row0, n0, As, Bs2);
    const int tid = threadIdx.x;
    const int lane = tid & 63, wave = tid >> 6;
    const int wm = (wave >> 1) * 64, wn = (wave & 1) * 64;
    const int l16 = lane & 15, quad = lane >> 4;
    float* Xt = X + (size_t)t * BB * NXX;
#pragma unroll
    for (int fm = 0; fm < 4; ++fm)
#pragma unroll
        for (int fn = 0; fn < 4; ++fn)
#pragma unroll
            for (int r = 0; r < 4; ++r) {
                int m = row0 + wm + fm * 16 + quad * 4 + r;
                int n = n0 + wn + fn * 16 + l16;
                float v = acc[fm][fn][r] + Xt[(size_t)m * NXX + n];
                Xt[(size_t)m * NXX + n] = v;
                if (n == NXX - 1) Y[(size_t)t * BB + m] = v;
            }
}

// ---------------------------------------------------------------------------
// Pass A: fused per-chunk zero-init recurrence. Block = (chunk c, 32 rows),
// 1024 threads (16 waves). Double-buffered Sb/Ub/Db -> ONE barrier per step;
// U/D for step j+1 prefetched into regs right after the barrier so the HBM
// latency hides under the MFMA phase. Writes every step's state to X (f32)
// and the chunk-end state to Gout slab c+1 (bf16).
// ---------------------------------------------------------------------------
__global__ __launch_bounds__(1024, 4) void k_scanA(
    const float* __restrict__ U, const float* __restrict__ Dm,
    const unsigned short* __restrict__ Bwb, const unsigned short* __restrict__ Ewb,
    const unsigned short* __restrict__ Wt,
    unsigned short* __restrict__ Gout,
    float* __restrict__ X)
{
    const int c   = blockIdx.x;          // chunk 0..31
    const int r0  = blockIdx.y * 32;     // batch-row base
    const int tid = threadIdx.x;         // 0..1023
    const int lane = tid & 63, wave = tid >> 6;   // wave 0..15
    const int l16 = lane & 15, quad = lane >> 4;

    __shared__ unsigned short Sb[2][32][520];   // state bf16, double-buffered
    __shared__ unsigned short Ub[2][32][136];   // U tile bf16, double-buffered
    __shared__ unsigned short Db[2][32][72];    // D tile bf16, double-buffered

    // staging coords (1024 threads: 32 rows x 32 col-groups)
    const int srow = tid >> 5;           // 0..31
    const int su   = (tid & 31) * 4;     // U: 4 floats
    const int sd   = (tid & 31) * 2;     // D: 2 floats

    // prologue: stage step 0 into buffer 0
    {
        const float* up = U + ((size_t)(c * CL) * BB + r0 + srow) * NUU + su;
        float4 a0 = *(const float4*)up;
        ushort4v h0 = { f2bf(a0.x), f2bf(a0.y), f2bf(a0.z), f2bf(a0.w) };
        *(ushort4v*)&Ub[0][srow][su] = h0;
        const float* dp = Dm + ((size_t)(c * CL) * BB + r0 + srow) * NDD + sd;
        float2 b0 = *(const float2*)dp;
        unsigned pk = (unsigned)f2bf(b0.x) | ((unsigned)f2bf(b0.y) << 16);
        *(unsigned*)&Db[0][srow][sd] = pk;
    }

    // per-lane 32-bit element offsets for the 2 n-frags of this wave
    int woff[2], bwoff[2], ewoff[2];
#pragma unroll
    for (int g = 0; g < 2; ++g) {
        int n = wave * 32 + g * 16 + l16;
        woff[g]  = n * NXX + quad * 8;
        bwoff[g] = n * NUU + quad * 8;
        ewoff[g] = n * NDD + quad * 8;
    }

    f32x4 acc[2][2];

    for (int j = 0; j < CL; ++j) {
        const int t   = c * CL + j;
        const int cur = j & 1, nxt = cur ^ 1;

        __syncthreads();   // buffers written last step (or prologue) now visible

        // ---- prefetch next step's U/D into regs (latency hides under MFMAs) ----
        float4 pu; float2 pd;
        if (j + 1 < CL) {
            pu = *(const float4*)(U + ((size_t)(t + 1) * BB + r0 + srow) * NUU + su);
            pd = *(const float2*)(Dm + ((size_t)(t + 1) * BB + r0 + srow) * NDD + sd);
        }

#pragma unroll
        for (int f = 0; f < 2; ++f)
#pragma unroll
            for (int g = 0; g < 2; ++g) acc[f][g] = (f32x4){0.f, 0.f, 0.f, 0.f};

        // ---- inj: U @ Bw^T  (K=128) ----
#pragma unroll
        for (int kk = 0; kk < 4; ++kk) {
            short8 a0 = *(const short8*)&Ub[cur][l16][kk * 32 + quad * 8];
            short8 a1 = *(const short8*)&Ub[cur][16 + l16][kk * 32 + quad * 8];
#pragma unroll
            for (int g = 0; g < 2; ++g) {
                short8 b = *(const short8*)(Bwb + bwoff[g] + kk * 32);
                acc[0][g] = __builtin_amdgcn_mfma_f32_16x16x32_bf16(a0, b, acc[0][g], 0, 0, 0);
                acc[1][g] = __builtin_amdgcn_mfma_f32_16x16x32_bf16(a1, b, acc[1][g], 0, 0, 0);
            }
        }
        // ---- inj: D @ Ew^T  (K=64) ----
#pragma unroll
        for (int kk = 0; kk < 2; ++kk) {
            short8 a0 = *(const short8*)&Db[cur][l16][kk * 32 + quad * 8];
            short8 a1 = *(const short8*)&Db[cur][16 + l16][kk * 32 + quad * 8];
#pragma unroll
            for (int g = 0; g < 2; ++g) {
                short8 b = *(const short8*)(Ewb + ewoff[g] + kk * 32);
                acc[0][g] = __builtin_amdgcn_mfma_f32_16x16x32_bf16(a0, b, acc[0][g], 0, 0, 0);
                acc[1][g] = __builtin_amdgcn_mfma_f32_16x16x32_bf16(a1, b, acc[1][g], 0, 0, 0);
            }
        }
        // ---- state @ W  (K=512) ----
        if (j > 0) {
#pragma unroll
            for (int kk = 0; kk < 16; ++kk) {
                short8 a0 = *(const short8*)&Sb[cur][l16][kk * 32 + quad * 8];
                short8 a1 = *(const short8*)&Sb[cur][16 + l16][kk * 32 + quad * 8];
#pragma unroll
                for (int g = 0; g < 2; ++g) {
                    short8 b = *(const short8*)(Wt + woff[g] + kk * 32);
                    acc[0][g] = __builtin_amdgcn_mfma_f32_16x16x32_bf16(a0, b, acc[0][g], 0, 0, 0);
                    acc[1][g] = __builtin_amdgcn_mfma_f32_16x16x32_bf16(a1, b, acc[1][g], 0, 0, 0);
                }
            }
        }

        // ---- write new state to OTHER buffer + X (f32) ----
#pragma unroll
        for (int f = 0; f < 2; ++f)
#pragma unroll
            for (int g = 0; g < 2; ++g) {
                int n = wave * 32 + g * 16 + l16;
#pragma unroll
                for (int rr = 0; rr < 4; ++rr) {
                    int mr = f * 16 + quad * 4 + rr;
                    float v = acc[f][g][rr];
                    unsigned short hb = f2bf(v);
                    Sb[nxt][mr][n] = hb;
                    X[((size_t)t * BB + r0 + mr) * NXX + n] = v;
                    if (j == CL - 1)
                        Gout[((size_t)(c + 1) * BB + r0 + mr) * NXX + n] = hb;
                }
            }

        // ---- convert prefetched U/D -> OTHER buffer ----
        if (j + 1 < CL) {
            ushort4v h0 = { f2bf(pu.x), f2bf(pu.y), f2bf(pu.z), f2bf(pu.w) };
            *(ushort4v*)&Ub[nxt][srow][su] = h0;
            unsigned pk = (unsigned)f2bf(pd.x) | ((unsigned)f2bf(pd.y) << 16);
            *(unsigned*)&Db[nxt][srow][sd] = pk;
        }
    }
}

// ---------------------------------------------------------------------------
extern "C" void kernel_launch(void* const* d_in, const int* in_sizes, int n_in,
                              void* d_out, int out_size, void* d_ws, size_t ws_size,
                              hipStream_t stream)
{
    const float* x   = (const float*)d_in[0];
    const float* U   = (const float*)d_in[1];
    const float* Dm  = (const float*)d_in[2];
    const float* Aw  = (const float*)d_in[3];
    const float* Asc = (const float*)d_in[4];
    const float* Bw  = (const float*)d_in[5];
    const float* Ew  = (const float*)d_in[6];

    float* Xout = (float*)d_out;
    float* Yout = Xout + (size_t)TT * BB * NXX;

    // ws layout (bf16): power slots 0..7 = W^{1..8}, 8..11 = W^{16,32,64,128};
    // Bwb 512x128; Ewb 512x64; G 33 slabs; vA 32; vB 32  (~32 MB total)
    unsigned short* powb = (unsigned short*)d_ws;
    unsigned short* Bwb  = powb + (size_t)12 * MS;
    unsigned short* Ewb  = Bwb + (size_t)NXX * NUU;
    unsigned short* Gbuf = Ewb + (size_t)NXX * NDD;
    unsigned short* vA   = Gbuf + (size_t)(NC + 1) * BS;
    unsigned short* vB   = vA + (size_t)NC * BS;

    dim3 blk(256);
    dim3 blkScan(1024);

    k_weff<<<dim3(512), blk, 0, stream>>>(Aw, Asc, powb);
    k_prep<<<dim3(224), blk, 0, stream>>>(Bw, Ew, x, Bwb, Ewb, Gbuf);

    // power products (T-space; slot p-1 = W^p for p=1..8); W^{16..128} ride
    // along inside the HS launches below.
    k_mulN<<<dim3(4, 4, 1), blk, 0, stream>>>(powb,
        make_int4(0, 0, 0, 0), make_int4(0, 0, 0, 0), make_int4(1, 0, 0, 0));
    k_mulN<<<dim3(4, 4, 2), blk, 0, stream>>>(powb,
        make_int4(1, 1, 0, 0), make_int4(0, 1, 0, 0), make_int4(2, 3, 0, 0));
    k_mulN<<<dim3(4, 4, 4), blk, 0, stream>>>(powb,
        make_int4(3, 3, 3, 3), make_int4(0, 1, 2, 3), make_int4(4, 5, 6, 7));

    // Pass A: zero-init chunk scans -> xA into X (f32), chunk-ends into G[1..32]
    k_scanA<<<dim3(NC, 8), blkScan, 0, stream>>>(
        U, Dm, Bwb, Ewb, powb, Gbuf, Xout);

    // Hillis-Steele prefix over chunk-start states, with the next squaring
    // (W^16, W^32, W^64, W^128) piggybacked as 2 extra grid-z slices.
    k_hs_sq<<<dim3(4, 2, NC + 2), blk, 0, stream>>>(Gbuf, vA, powb + (size_t)7 * MS, 1,
                                                    powb, 7, 8);
    k_hs_sq<<<dim3(4, 2, NC + 2), blk, 0, stream>>>(vA, vB, powb + (size_t)8 * MS, 2,
                                                    powb, 8, 9);
    k_hs_sq<<<dim3(4, 2, NC + 2), blk, 0, stream>>>(vB, vA, powb + (size_t)9 * MS, 4,
                                                    powb, 9, 10);
    k_hs_sq<<<dim3(4, 2, NC + 2), blk, 0, stream>>>(vA, vB, powb + (size_t)10 * MS, 8,
                                                    powb, 10, 11);
    k_hs_sq<<<dim3(4, 2, NC), blk, 0, stream>>>(vB, vA, powb + (size_t)11 * MS, 16,
                                                powb, 0, 0);

    // Seed-correction GEMM: X[t] += vA[t/8] @ W^{(t%8)+1}; writes Y
    k_xcorr<<<dim3(4, 2, TT), blk, 0, stream>>>(vA, powb, Xout, Yout);
}